// Round 5
// baseline (178.646 us; speedup 1.0000x reference)
//
#include <hip/hip_runtime.h>

// Round 5 = retry of round 4 submission (bench infra failed: container
// acquisition error, kernel never ran). Kernel unchanged from round 3 design.
// Problem constants: B=16 batches, A=5 agents, C=512 channels, H=W=16.
#define NB 16
#define NA 5
#define NC 512
#define HW 256        // 16*16

typedef _Float16 h8 __attribute__((ext_vector_type(8)));   // 16 B = one ds_read_b128

static __device__ __forceinline__ h8 splat8(float v) {
    const _Float16 h = (_Float16)v;
    h8 r = {h, h, h, h, h, h, h, h};
    return r;
}

// Wave-uniform -> SGPR (trans entries depend only on block indices).
static __device__ __forceinline__ float rfl(float v) {
    return __builtin_bit_cast(float,
        __builtin_amdgcn_readfirstlane(__builtin_bit_cast(int, v)));
}

// Two bilinear samples of a staged fp16 slab, batched: all 8 addresses and all
// 8 masked weights are computed BEFORE the 8 ds_read_b128 are issued (ILP).
// ws* are stage-2 weights (already border-masked); zero-padding via weight=0 +
// clamped address. (Identical math to the session's verified fused kernel.)
static __device__ __forceinline__ h8 rot_sample2(const h8* __restrict__ src,
        float xA, float yA, float wA,
        float xB, float yB, float wB) {
    const float fxA = floorf(xA), fyA = floorf(yA);
    const float fxB = floorf(xB), fyB = floorf(yB);
    const int ixA = (int)fxA, iyA = (int)fyA;
    const int ixB = (int)fxB, iyB = (int)fyB;
    const float wxA1 = xA - fxA, wyA1 = yA - fyA;
    const float wxB1 = xB - fxB, wyB1 = yB - fyB;
    const float mxA0 = (ixA     >= 0 && ixA     < 16) ? 1.0f - wxA1 : 0.0f;
    const float mxA1 = (ixA + 1 >= 0 && ixA + 1 < 16) ? wxA1 : 0.0f;
    const float myA0 = (iyA     >= 0 && iyA     < 16) ? (1.0f - wyA1) * wA : 0.0f;
    const float myA1 = (iyA + 1 >= 0 && iyA + 1 < 16) ? wyA1 * wA : 0.0f;
    const float mxB0 = (ixB     >= 0 && ixB     < 16) ? 1.0f - wxB1 : 0.0f;
    const float mxB1 = (ixB + 1 >= 0 && ixB + 1 < 16) ? wxB1 : 0.0f;
    const float myB0 = (iyB     >= 0 && iyB     < 16) ? (1.0f - wyB1) * wB : 0.0f;
    const float myB1 = (iyB + 1 >= 0 && iyB + 1 < 16) ? wyB1 * wB : 0.0f;
    const int cxA0 = min(max(ixA, 0), 15), cxA1 = min(max(ixA + 1, 0), 15);
    const int cyA0 = min(max(iyA, 0), 15), cyA1 = min(max(iyA + 1, 0), 15);
    const int cxB0 = min(max(ixB, 0), 15), cxB1 = min(max(ixB + 1, 0), 15);
    const int cyB0 = min(max(iyB, 0), 15), cyB1 = min(max(iyB + 1, 0), 15);
    // 8 independent LDS loads, issued back-to-back
    const h8 vA00 = src[cyA0 * 16 + cxA0];
    const h8 vA01 = src[cyA0 * 16 + cxA1];
    const h8 vA10 = src[cyA1 * 16 + cxA0];
    const h8 vA11 = src[cyA1 * 16 + cxA1];
    const h8 vB00 = src[cyB0 * 16 + cxB0];
    const h8 vB01 = src[cyB0 * 16 + cxB1];
    const h8 vB10 = src[cyB1 * 16 + cxB0];
    const h8 vB11 = src[cyB1 * 16 + cxB1];
    return (vA00 * splat8(mxA0) + vA01 * splat8(mxA1)) * splat8(myA0)
         + (vA10 * splat8(mxA0) + vA11 * splat8(mxA1)) * splat8(myA1)
         + (vB00 * splat8(mxB0) + vB01 * splat8(mxB1)) * splat8(myB0)
         + (vB10 * splat8(mxB0) + vB11 * splat8(mxB1)) * splat8(myB1);
}

// ONE BARRIER PER BLOCK. Block = (batch b, 8-channel slab); stage the 5 agent
// slabs to fp16 LDS once, sync once, then LDS is read-only: compute all 5
// agents' outputs with the fused 16-tap two-stage gather (no lds_rot, no
// phase barriers). After the barrier the block's 4 waves run fully
// independently -- the R2/R3 kernels lost 4-5x to barrier-serialized LDS
// phases (VALUBusy 10.8%, occupancy 18.5%). Residual slabs are re-read from
// L2-hot global per agent (keeps VGPR low; avoids the R2 remat trap).
// Block mapping b = idx & 15 interleaves batches across CUs for balance.
__global__ __launch_bounds__(256, 4) void fafmimo_fused1b_kernel(
    const float* __restrict__ feat,   // [A*B][C][256], feat[a*B+b] = local[b][a]
    const float* __restrict__ trans,  // [B][A][A][4][4]
    const int*   __restrict__ numa,   // [B][A], use [:,0]
    float*       __restrict__ out)    // [A*B][C][256]
{
    __shared__ h8 lds_nb[NA][HW];     // 20 KiB -> LDS caps 8 blocks/CU

    const int p = threadIdx.x;
    const int x = p & 15, y = p >> 4;

    const int b  = blockIdx.x & 15;           // interleave batches
    const int c0 = (blockIdx.x >> 4) << 3;    // 64 channel slabs
    const int n  = numa[b * NA];              // block-uniform

    // ---- stage the a<n agent slabs to fp16 LDS (each feat elem read once) ----
#pragma unroll
    for (int a = 0; a < NA; ++a) {
        if (a < n) {                  // block-uniform
            const float* src = feat + ((a * NB + b) * NC + c0) * HW + p;
            h8 v;
#pragma unroll
            for (int k = 0; k < 8; ++k) v[k] = (_Float16)src[k * HW];
            lds_nb[a][p] = v;
        }
    }
    __syncthreads();                  // the ONLY barrier

#pragma unroll
    for (int i = 0; i < NA; ++i) {
        // residual re-load (L2-hot; issued before the gather, consumed at store)
        const float* own = feat + ((i * NB + b) * NC + c0) * HW + p;
        float ownv[8];
#pragma unroll
        for (int k = 0; k < 8; ++k) ownv[k] = own[k * HW];

        float psum[8];
#pragma unroll
        for (int k = 0; k < 8; ++k) psum[k] = 0.0f;

        if (n > 1 && i < n) {         // block-uniform
#pragma unroll
            for (int jj = 0; jj < 4; ++jj) {
                const int j = jj + (jj >= i);
                if (j < n) {          // block-uniform
                    const float* tw = trans + (((b * NA) + i) * NA + j) * 16;
                    const float r00 = rfl(tw[0]), r01 = rfl(tw[1]);
                    const float r10 = rfl(tw[4]), r11 = rfl(tw[5]);

                    // stage-2 (translation) constants
                    const float dx =  0.25f * rfl(tw[3]);
                    const float dy = -0.25f * rfl(tw[7]);
                    const float fdx = floorf(dx), fdy = floorf(dy);
                    const float tx1 = dx - fdx, tx0 = 1.0f - tx1;
                    const float ty1 = dy - fdy, ty0 = 1.0f - ty1;
                    const int ox = x + (int)fdx;
                    const int oy = y + (int)fdy;
                    const bool inx0 = (ox     >= 0) && (ox     < 16);
                    const bool inx1 = (ox + 1 >= 0) && (ox + 1 < 16);
                    const bool iny0 = (oy     >= 0) && (oy     < 16);
                    const bool iny1 = (oy + 1 >= 0) && (oy + 1 < 16);
                    const float ws00 = (inx0 && iny0) ? tx0 * ty0 : 0.0f;
                    const float ws10 = (inx1 && iny0) ? tx1 * ty0 : 0.0f;
                    const float ws01 = (inx0 && iny1) ? tx0 * ty1 : 0.0f;
                    const float ws11 = (inx1 && iny1) ? tx1 * ty1 : 0.0f;

                    // rotation coords at the 2x2 stage-2 tap positions
                    const float fox = (float)ox - 7.5f;
                    const float foy = (float)oy - 7.5f;
                    const float bxr = r00 * fox + r01 * foy + 7.5f;
                    const float byr = r10 * fox + r11 * foy + 7.5f;

                    const h8* srcj = &lds_nb[j][0];
                    h8 pair = rot_sample2(srcj,
                        bxr,       byr,       ws00,
                        bxr + r00, byr + r10, ws10);
                    pair   += rot_sample2(srcj,
                        bxr + r01,       byr + r11,       ws01,
                        bxr + r00 + r01, byr + r10 + r11, ws11);
                    // f32 accumulation across pairs (fp16 only within a pair)
#pragma unroll
                    for (int k = 0; k < 8; ++k) psum[k] += (float)pair[k];
                }
            }
        }

        float* dst = out + ((i * NB + b) * NC + c0) * HW + p;
#pragma unroll
        for (int k = 0; k < 8; ++k) dst[k * HW] = ownv[k] + psum[k];
    }
}

extern "C" void kernel_launch(void* const* d_in, const int* in_sizes, int n_in,
                              void* d_out, int out_size, void* d_ws, size_t ws_size,
                              hipStream_t stream) {
    const float* feat  = (const float*)d_in[0];
    const float* trans = (const float*)d_in[1];
    const int*   numa  = (const int*)d_in[2];
    float* out = (float*)d_out;

    fafmimo_fused1b_kernel<<<dim3(NB * 64), dim3(256), 0, stream>>>(
        feat, trans, numa, out);
}

// Round 6
// 136.932 us; speedup vs baseline: 1.3046x; 1.3046x over previous
//
#include <hip/hip_runtime.h>

// Problem constants: B=16 batches, A=5 agents, C=512 channels, H=W=16.
#define NB 16
#define NA 5
#define NC 512
#define HW 256        // 16*16

typedef _Float16 h8 __attribute__((ext_vector_type(8)));   // 16 B = one ds_read_b128

static __device__ __forceinline__ h8 splat8(float v) {
    const _Float16 h = (_Float16)v;
    h8 r = {h, h, h, h, h, h, h, h};
    return r;
}

// Wave-uniform -> SGPR (trans entries depend only on block indices).
static __device__ __forceinline__ float rfl(float v) {
    return __builtin_bit_cast(float,
        __builtin_amdgcn_readfirstlane(__builtin_bit_cast(int, v)));
}

// Two bilinear samples of a staged fp16 slab, batched: all 8 addresses and all
// 8 masked weights computed BEFORE the 8 ds_read_b128 are issued (ILP).
static __device__ __forceinline__ h8 rot_sample2(const h8* __restrict__ src,
        float xA, float yA, float wA,
        float xB, float yB, float wB) {
    const float fxA = floorf(xA), fyA = floorf(yA);
    const float fxB = floorf(xB), fyB = floorf(yB);
    const int ixA = (int)fxA, iyA = (int)fyA;
    const int ixB = (int)fxB, iyB = (int)fyB;
    const float wxA1 = xA - fxA, wyA1 = yA - fyA;
    const float wxB1 = xB - fxB, wyB1 = yB - fyB;
    const float mxA0 = (ixA     >= 0 && ixA     < 16) ? 1.0f - wxA1 : 0.0f;
    const float mxA1 = (ixA + 1 >= 0 && ixA + 1 < 16) ? wxA1 : 0.0f;
    const float myA0 = (iyA     >= 0 && iyA     < 16) ? (1.0f - wyA1) * wA : 0.0f;
    const float myA1 = (iyA + 1 >= 0 && iyA + 1 < 16) ? wyA1 * wA : 0.0f;
    const float mxB0 = (ixB     >= 0 && ixB     < 16) ? 1.0f - wxB1 : 0.0f;
    const float mxB1 = (ixB + 1 >= 0 && ixB + 1 < 16) ? wxB1 : 0.0f;
    const float myB0 = (iyB     >= 0 && iyB     < 16) ? (1.0f - wyB1) * wB : 0.0f;
    const float myB1 = (iyB + 1 >= 0 && iyB + 1 < 16) ? wyB1 * wB : 0.0f;
    const int cxA0 = min(max(ixA, 0), 15), cxA1 = min(max(ixA + 1, 0), 15);
    const int cyA0 = min(max(iyA, 0), 15), cyA1 = min(max(iyA + 1, 0), 15);
    const int cxB0 = min(max(ixB, 0), 15), cxB1 = min(max(ixB + 1, 0), 15);
    const int cyB0 = min(max(iyB, 0), 15), cyB1 = min(max(iyB + 1, 0), 15);
    const h8 vA00 = src[cyA0 * 16 + cxA0];
    const h8 vA01 = src[cyA0 * 16 + cxA1];
    const h8 vA10 = src[cyA1 * 16 + cxA0];
    const h8 vA11 = src[cyA1 * 16 + cxA1];
    const h8 vB00 = src[cyB0 * 16 + cxB0];
    const h8 vB01 = src[cyB0 * 16 + cxB1];
    const h8 vB10 = src[cyB1 * 16 + cxB0];
    const h8 vB11 = src[cyB1 * 16 + cxB1];
    return (vA00 * splat8(mxA0) + vA01 * splat8(mxA1)) * splat8(myA0)
         + (vA10 * splat8(mxA0) + vA11 * splat8(mxA1)) * splat8(myA1)
         + (vB00 * splat8(mxB0) + vB01 * splat8(mxB1)) * splat8(myB0)
         + (vB10 * splat8(mxB0) + vB11 * splat8(mxB1)) * splat8(myB1);
}

// ONE BARRIER + SPILL FIX. Round 5's version fully unrolled the i-loop
// (#pragma unroll): LLVM hoisted all 5 agents' residual loads and interleaved
// 20 pairs of gathers -> spill to scratch (WRITE_SIZE 114 MB vs 41.9 MB
// output, kernel 107 us). This version forces `#pragma unroll 1` on the
// i-loop so only ONE agent's working set is live (~100 VGPR, no spill);
// residual loads are issued at the top of each iteration and hide under that
// iteration's gather. LDS staged once, read-only after the single barrier.
__global__ __launch_bounds__(256, 4) void fafmimo_fused1b2_kernel(
    const float* __restrict__ feat,   // [A*B][C][256], feat[a*B+b] = local[b][a]
    const float* __restrict__ trans,  // [B][A][A][4][4]
    const int*   __restrict__ numa,   // [B][A], use [:,0]
    float*       __restrict__ out)    // [A*B][C][256]
{
    __shared__ h8 lds_nb[NA][HW];     // 20 KiB -> LDS allows 8 blocks/CU

    const int p = threadIdx.x;
    const int x = p & 15, y = p >> 4;

    const int b  = blockIdx.x & 15;           // interleave batches
    const int c0 = (blockIdx.x >> 4) << 3;    // 64 channel slabs
    const int n  = numa[b * NA];              // block-uniform

    // ---- stage the a<n agent slabs to fp16 LDS (each feat elem read once) ----
#pragma unroll
    for (int a = 0; a < NA; ++a) {
        if (a < n) {                  // block-uniform
            const float* src = feat + ((a * NB + b) * NC + c0) * HW + p;
            h8 v;
#pragma unroll
            for (int k = 0; k < 8; ++k) v[k] = (_Float16)src[k * HW];
            lds_nb[a][p] = v;
        }
    }
    __syncthreads();                  // the ONLY barrier

#pragma unroll 1                      // CRITICAL: one agent's regs live at a time
    for (int i = 0; i < NA; ++i) {
        // residual re-load (L2-hot), issued first, consumed only at the store
        const float* own = feat + ((i * NB + b) * NC + c0) * HW + p;
        float ownv[8];
#pragma unroll
        for (int k = 0; k < 8; ++k) ownv[k] = own[k * HW];

        float psum[8];
#pragma unroll
        for (int k = 0; k < 8; ++k) psum[k] = 0.0f;

        if (n > 1 && i < n) {         // block-uniform
#pragma unroll
            for (int jj = 0; jj < 4; ++jj) {
                const int j = jj + (jj >= i);
                if (j < n) {          // block-uniform
                    const float* tw = trans + (((b * NA) + i) * NA + j) * 16;
                    const float r00 = rfl(tw[0]), r01 = rfl(tw[1]);
                    const float r10 = rfl(tw[4]), r11 = rfl(tw[5]);

                    // stage-2 (translation) constants
                    const float dx =  0.25f * rfl(tw[3]);
                    const float dy = -0.25f * rfl(tw[7]);
                    const float fdx = floorf(dx), fdy = floorf(dy);
                    const float tx1 = dx - fdx, tx0 = 1.0f - tx1;
                    const float ty1 = dy - fdy, ty0 = 1.0f - ty1;
                    const int ox = x + (int)fdx;
                    const int oy = y + (int)fdy;
                    const bool inx0 = (ox     >= 0) && (ox     < 16);
                    const bool inx1 = (ox + 1 >= 0) && (ox + 1 < 16);
                    const bool iny0 = (oy     >= 0) && (oy     < 16);
                    const bool iny1 = (oy + 1 >= 0) && (oy + 1 < 16);
                    const float ws00 = (inx0 && iny0) ? tx0 * ty0 : 0.0f;
                    const float ws10 = (inx1 && iny0) ? tx1 * ty0 : 0.0f;
                    const float ws01 = (inx0 && iny1) ? tx0 * ty1 : 0.0f;
                    const float ws11 = (inx1 && iny1) ? tx1 * ty1 : 0.0f;

                    // rotation coords at the 2x2 stage-2 tap positions
                    const float fox = (float)ox - 7.5f;
                    const float foy = (float)oy - 7.5f;
                    const float bxr = r00 * fox + r01 * foy + 7.5f;
                    const float byr = r10 * fox + r11 * foy + 7.5f;

                    const h8* srcj = &lds_nb[j][0];
                    h8 pair = rot_sample2(srcj,
                        bxr,       byr,       ws00,
                        bxr + r00, byr + r10, ws10);
                    pair   += rot_sample2(srcj,
                        bxr + r01,       byr + r11,       ws01,
                        bxr + r00 + r01, byr + r10 + r11, ws11);
                    // f32 accumulation across pairs (fp16 only within a pair)
#pragma unroll
                    for (int k = 0; k < 8; ++k) psum[k] += (float)pair[k];
                }
            }
        }

        float* dst = out + ((i * NB + b) * NC + c0) * HW + p;
#pragma unroll
        for (int k = 0; k < 8; ++k) dst[k * HW] = ownv[k] + psum[k];
    }
}

extern "C" void kernel_launch(void* const* d_in, const int* in_sizes, int n_in,
                              void* d_out, int out_size, void* d_ws, size_t ws_size,
                              hipStream_t stream) {
    const float* feat  = (const float*)d_in[0];
    const float* trans = (const float*)d_in[1];
    const int*   numa  = (const int*)d_in[2];
    float* out = (float*)d_out;

    fafmimo_fused1b2_kernel<<<dim3(NB * 64), dim3(256), 0, stream>>>(
        feat, trans, numa, out);
}

// Round 7
// 122.107 us; speedup vs baseline: 1.4630x; 1.1214x over previous
//
#include <hip/hip_runtime.h>

// Problem constants: B=16 batches, A=5 agents, C=512 channels, H=W=16.
#define NB 16
#define NA 5
#define NC 512
#define HW 256        // 16*16

typedef _Float16 h8 __attribute__((ext_vector_type(8)));   // 16 B = one ds_read_b128

static __device__ __forceinline__ h8 splat8(float v) {
    const _Float16 h = (_Float16)v;
    h8 r = {h, h, h, h, h, h, h, h};
    return r;
}

// Wave-uniform -> SGPR (trans entries depend only on block indices).
static __device__ __forceinline__ float rfl(float v) {
    return __builtin_bit_cast(float,
        __builtin_amdgcn_readfirstlane(__builtin_bit_cast(int, v)));
}

// XOR bank swizzle: [y][x] h8 layout puts bank group = x%8 independent of y,
// so rotated tap clusters (similar x, varying y) collide (measured 1.27M
// conflict cycles in R6). x ^= (y&7) decorrelates; bijective within each row.
static __device__ __forceinline__ int lidx(int yy, int xx) {
    return yy * 16 + (xx ^ (yy & 7));
}

// Two bilinear samples of a staged fp16 slab, batched: all 8 addresses and all
// 8 masked weights computed BEFORE the 8 ds_read_b128 are issued (ILP).
// ws* are stage-2 weights (already border-masked); zero-padding via weight=0 +
// clamped address. Math identical to the verified R0/R1 kernels.
static __device__ __forceinline__ h8 rot_sample2(const h8* __restrict__ src,
        float xA, float yA, float wA,
        float xB, float yB, float wB) {
    const float fxA = floorf(xA), fyA = floorf(yA);
    const float fxB = floorf(xB), fyB = floorf(yB);
    const int ixA = (int)fxA, iyA = (int)fyA;
    const int ixB = (int)fxB, iyB = (int)fyB;
    const float wxA1 = xA - fxA, wyA1 = yA - fyA;
    const float wxB1 = xB - fxB, wyB1 = yB - fyB;
    const float mxA0 = (ixA     >= 0 && ixA     < 16) ? 1.0f - wxA1 : 0.0f;
    const float mxA1 = (ixA + 1 >= 0 && ixA + 1 < 16) ? wxA1 : 0.0f;
    const float myA0 = (iyA     >= 0 && iyA     < 16) ? (1.0f - wyA1) * wA : 0.0f;
    const float myA1 = (iyA + 1 >= 0 && iyA + 1 < 16) ? wyA1 * wA : 0.0f;
    const float mxB0 = (ixB     >= 0 && ixB     < 16) ? 1.0f - wxB1 : 0.0f;
    const float mxB1 = (ixB + 1 >= 0 && ixB + 1 < 16) ? wxB1 : 0.0f;
    const float myB0 = (iyB     >= 0 && iyB     < 16) ? (1.0f - wyB1) * wB : 0.0f;
    const float myB1 = (iyB + 1 >= 0 && iyB + 1 < 16) ? wyB1 * wB : 0.0f;
    const int cxA0 = min(max(ixA, 0), 15), cxA1 = min(max(ixA + 1, 0), 15);
    const int cyA0 = min(max(iyA, 0), 15), cyA1 = min(max(iyA + 1, 0), 15);
    const int cxB0 = min(max(ixB, 0), 15), cxB1 = min(max(ixB + 1, 0), 15);
    const int cyB0 = min(max(iyB, 0), 15), cyB1 = min(max(iyB + 1, 0), 15);
    const h8 vA00 = src[lidx(cyA0, cxA0)];
    const h8 vA01 = src[lidx(cyA0, cxA1)];
    const h8 vA10 = src[lidx(cyA1, cxA0)];
    const h8 vA11 = src[lidx(cyA1, cxA1)];
    const h8 vB00 = src[lidx(cyB0, cxB0)];
    const h8 vB01 = src[lidx(cyB0, cxB1)];
    const h8 vB10 = src[lidx(cyB1, cxB0)];
    const h8 vB11 = src[lidx(cyB1, cxB1)];
    return (vA00 * splat8(mxA0) + vA01 * splat8(mxA1)) * splat8(myA0)
         + (vA10 * splat8(mxA0) + vA11 * splat8(mxA1)) * splat8(myA1)
         + (vB00 * splat8(mxB0) + vB01 * splat8(mxB1)) * splat8(myB0)
         + (vB10 * splat8(mxB0) + vB11 * splat8(mxB1)) * splat8(myB1);
}

// FINE-GRAIN + BACKFILL. R6 (block = (b,slab), all 5 agents, grid 1024 = exact
// CU capacity) measured OccupancyPercent 14%: work/block spans 0..20 pairs and
// fast blocks can't be replaced -> long n=5 tail at 1-2 blocks/CU. This
// version: block = (agent i, batch b, 8-ch slab), grid 5120. Max 4 pairs per
// block (5x finer tail); no-work blocks exit immediately and the HW dispatcher
// backfills. Staging redundancy (slab staged by <=4 consumers) is L2/L3-hot.
// One barrier; fused 16-tap gather; unroll 1 keeps VGPR ~R6's 44 -> 8 w/SIMD.
__global__ __launch_bounds__(256, 4) void fafmimo_finegrain_kernel(
    const float* __restrict__ feat,   // [A*B][C][256], feat[a*B+b] = local[b][a]
    const float* __restrict__ trans,  // [B][A][A][4][4]
    const int*   __restrict__ numa,   // [B][A], use [:,0]
    float*       __restrict__ out)    // [A*B][C][256]
{
    __shared__ h8 lds_nb[4][HW];      // 16 KiB (neighbor slabs only)

    const int p = threadIdx.x;
    const int x = p & 15, y = p >> 4;

    const int idx  = blockIdx.x;          // 5120 = 5 * 16 * 64
    const int i    = idx % NA;
    const int rest = idx / NA;
    const int b    = rest & 15;
    const int c0   = (rest >> 4) << 3;
    const int n    = numa[b * NA];        // block-uniform
    const bool work = (i < n) && (n > 1); // block-uniform

    // residual loads issued up front; consumed only at the store
    const float* own = feat + ((i * NB + b) * NC + c0) * HW + p;
    float ownv[8];
#pragma unroll
    for (int k = 0; k < 8; ++k) ownv[k] = own[k * HW];

    float psum[8];
#pragma unroll
    for (int k = 0; k < 8; ++k) psum[k] = 0.0f;

    if (work) {
        // ---- stage the (n-1 <= 4) neighbor slabs to swizzled fp16 LDS ----
#pragma unroll
        for (int jj = 0; jj < 4; ++jj) {
            const int j = jj + (jj >= i);
            if (j < n) {              // block-uniform
                const float* src = feat + ((j * NB + b) * NC + c0) * HW + p;
                h8 v;
#pragma unroll
                for (int k = 0; k < 8; ++k) v[k] = (_Float16)src[k * HW];
                lds_nb[jj][lidx(y, x)] = v;
            }
        }
        __syncthreads();              // the ONLY barrier

        // ---- fused two-stage 16-tap gather, one pair at a time ----
#pragma unroll 1                      // keep one pair's regs live (R5 spill lesson)
        for (int jj = 0; jj < 4; ++jj) {
            const int j = jj + (jj >= i);
            if (j < n) {              // block-uniform
                const float* tw = trans + (((b * NA) + i) * NA + j) * 16;
                const float r00 = rfl(tw[0]), r01 = rfl(tw[1]);
                const float r10 = rfl(tw[4]), r11 = rfl(tw[5]);

                // stage-2 (translation) constants
                const float dx =  0.25f * rfl(tw[3]);
                const float dy = -0.25f * rfl(tw[7]);
                const float fdx = floorf(dx), fdy = floorf(dy);
                const float tx1 = dx - fdx, tx0 = 1.0f - tx1;
                const float ty1 = dy - fdy, ty0 = 1.0f - ty1;
                const int ox = x + (int)fdx;
                const int oy = y + (int)fdy;
                const bool inx0 = (ox     >= 0) && (ox     < 16);
                const bool inx1 = (ox + 1 >= 0) && (ox + 1 < 16);
                const bool iny0 = (oy     >= 0) && (oy     < 16);
                const bool iny1 = (oy + 1 >= 0) && (oy + 1 < 16);
                const float ws00 = (inx0 && iny0) ? tx0 * ty0 : 0.0f;
                const float ws10 = (inx1 && iny0) ? tx1 * ty0 : 0.0f;
                const float ws01 = (inx0 && iny1) ? tx0 * ty1 : 0.0f;
                const float ws11 = (inx1 && iny1) ? tx1 * ty1 : 0.0f;

                // rotation coords at the 2x2 stage-2 tap positions
                const float fox = (float)ox - 7.5f;
                const float foy = (float)oy - 7.5f;
                const float bxr = r00 * fox + r01 * foy + 7.5f;
                const float byr = r10 * fox + r11 * foy + 7.5f;

                const h8* srcj = &lds_nb[jj][0];
                h8 pair = rot_sample2(srcj,
                    bxr,       byr,       ws00,
                    bxr + r00, byr + r10, ws10);
                pair   += rot_sample2(srcj,
                    bxr + r01,       byr + r11,       ws01,
                    bxr + r00 + r01, byr + r10 + r11, ws11);
                // f32 accumulation across pairs (fp16 only within a pair)
#pragma unroll
                for (int k = 0; k < 8; ++k) psum[k] += (float)pair[k];
            }
        }
    }

    float* dst = out + ((i * NB + b) * NC + c0) * HW + p;
#pragma unroll
    for (int k = 0; k < 8; ++k) dst[k * HW] = ownv[k] + psum[k];
}

extern "C" void kernel_launch(void* const* d_in, const int* in_sizes, int n_in,
                              void* d_out, int out_size, void* d_ws, size_t ws_size,
                              hipStream_t stream) {
    const float* feat  = (const float*)d_in[0];
    const float* trans = (const float*)d_in[1];
    const int*   numa  = (const int*)d_in[2];
    float* out = (float*)d_out;

    fafmimo_finegrain_kernel<<<dim3(NA * NB * 64), dim3(256), 0, stream>>>(
        feat, trans, numa, out);
}

// Round 8
// 95.013 us; speedup vs baseline: 1.8802x; 1.2852x over previous
//
#include <hip/hip_runtime.h>

// Problem constants: B=16 batches, A=5 agents, C=512 channels, H=W=16.
#define NB 16
#define NA 5
#define NC 512
#define HW 256        // 16*16
#define NBLK 2048     // 8 blocks/CU worth of grid; items via stride
#define NTOT 5120     // 5*16*64 8-channel items

typedef _Float16 h8 __attribute__((ext_vector_type(8)));   // 16 B = one ds_read_b128

static __device__ __forceinline__ h8 splat8(float v) {
    const _Float16 h = (_Float16)v;
    h8 r = {h, h, h, h, h, h, h, h};
    return r;
}

// Force wave-uniform values into SGPRs (trans entries depend only on block
// indices; scalar regs keep the pair-uniform weight math off the VALU).
static __device__ __forceinline__ float rfl(float v) {
    return __builtin_bit_cast(float,
        __builtin_amdgcn_readfirstlane(__builtin_bit_cast(int, v)));
}

// This is the measured-best structure of the session (dur_us 96.8): two-phase
// pipelined, 2048 persistent blocks, 3 barriers/item. Rounds 2-7 disproved
// every restructure: coarse agent-blocks (remat, 51us), 4-ch variant (104 dur),
// barrier-free fused 16-tap (spill 107us; fixed-spill 65us; fine-grain 49us),
// and LDS XOR swizzle (conflicts UP 1.27M->2.2M). Single delta vs the 96.8
// kernel: own[] removed from the prefetched Item (-16 VGPR across cur+nxt,
// the R2/R5 pressure lesson); residual loads issue at gather-phase start,
// L2-hot, consumed only at the store -> hidden under phases A+B.
struct Item {
    int i, b, c0, n;      // wave-uniform -> SGPR
    bool work;
    float nb[4][8];       // neighbor slabs (this thread's pixel), f32 until LDS write
    float tr[4][6];       // r00 r01 w03 r10 r11 w13  (uniform, SGPR via rfl)
};

// Issue all global loads for item `idx`; values land later (regs), hidden by
// the previous item's gather phase.
static __device__ __forceinline__ Item prefetch_item(
        const float* __restrict__ feat, const float* __restrict__ trans,
        const int* __restrict__ numa, int idx, int p) {
    Item it;
    const int g = idx & 63;
    const int r = idx >> 6;
    it.i = r % NA;
    it.b = r / NA;
    it.c0 = g << 3;
    it.n = numa[it.b * NA];
    it.work = (it.i < it.n) && (it.n > 1);
    if (it.work) {
#pragma unroll
        for (int jj = 0; jj < 4; ++jj) {
            const int j = jj + (jj >= it.i);
            if (j < it.n) {                    // block-uniform
                const float* tw = trans + (((it.b * NA) + it.i) * NA + j) * 16;
                it.tr[jj][0] = rfl(tw[0]);     // r00
                it.tr[jj][1] = rfl(tw[1]);     // r01
                it.tr[jj][2] = rfl(tw[3]);     // w03 (tx source)
                it.tr[jj][3] = rfl(tw[4]);     // r10
                it.tr[jj][4] = rfl(tw[5]);     // r11
                it.tr[jj][5] = rfl(tw[7]);     // w13 (ty source)
                const float* src = feat + ((j * NB + it.b) * NC + it.c0) * HW + p;
#pragma unroll
                for (int k = 0; k < 8; ++k) it.nb[jj][k] = src[k * HW];
            }
        }
    }
    return it;
}

__global__ __launch_bounds__(256) void fafmimo_twophase2_kernel(
    const float* __restrict__ feat,   // [A*B][C][256], feat[a*B+b] = local[b][a]
    const float* __restrict__ trans,  // [B][A][A][4][4]
    const int*   __restrict__ numa,   // [B][A], use [:,0]
    float*       __restrict__ out)    // [A*B][C][256]
{
    __shared__ h8 lds_nb[4][HW];      // 16 KiB  staged neighbor slabs
    __shared__ h8 lds_rot[4][HW];     // 16 KiB  rotated intermediates

    const int p = threadIdx.x;
    const int x = p & 15, y = p >> 4;
    const float fx = (float)x - 7.5f;
    const float fy = (float)y - 7.5f;
    bool dirty = false;               // block-uniform

    int idx = blockIdx.x;
    Item cur = prefetch_item(feat, trans, numa, idx, p);

    while (true) {
        // ---- LDS stage phase for cur ----
        if (cur.work) {
            if (dirty) __syncthreads();       // prior item's LDS readers done
#pragma unroll
            for (int jj = 0; jj < 4; ++jj) {
                const int j = jj + (jj >= cur.i);
                if (j < cur.n) {
                    h8 v;
#pragma unroll
                    for (int k = 0; k < 8; ++k) v[k] = (_Float16)cur.nb[jj][k];
                    lds_nb[jj][p] = v;
                }
            }
            __syncthreads();
            dirty = true;
        }

        // ---- prefetch next item (loads overlap phases A/B below) ----
        const int nidx = idx + NBLK;
        const bool more = nidx < NTOT;        // block-uniform
        Item nxt;
        if (more) nxt = prefetch_item(feat, trans, numa, nidx, p);

        // ---- residual loads: issued here (L2-hot), consumed only at store ----
        const float* own = feat + ((cur.i * NB + cur.b) * NC + cur.c0) * HW + p;
        float ownv[8];
#pragma unroll
        for (int k = 0; k < 8; ++k) ownv[k] = own[k * HW];

        float psum[8];
#pragma unroll
        for (int k = 0; k < 8; ++k) psum[k] = 0.0f;

        if (cur.work) {
            // ---- Phase A: rotation bilinear at this thread's pixel ----
#pragma unroll
            for (int jj = 0; jj < 4; ++jj) {
                const int j = jj + (jj >= cur.i);
                if (j < cur.n) {
                    const float r00 = cur.tr[jj][0], r01 = cur.tr[jj][1];
                    const float r10 = cur.tr[jj][3], r11 = cur.tr[jj][4];
                    const float bx = r00 * fx + r01 * fy + 7.5f;
                    const float by = r10 * fx + r11 * fy + 7.5f;
                    const float fbx = floorf(bx), fby = floorf(by);
                    const int ix = (int)fbx, iy = (int)fby;
                    const float wx1 = bx - fbx, wy1 = by - fby;
                    const float mx0 = (ix     >= 0 && ix     < 16) ? 1.0f - wx1 : 0.0f;
                    const float mx1 = (ix + 1 >= 0 && ix + 1 < 16) ? wx1 : 0.0f;
                    const float my0 = (iy     >= 0 && iy     < 16) ? 1.0f - wy1 : 0.0f;
                    const float my1 = (iy + 1 >= 0 && iy + 1 < 16) ? wy1 : 0.0f;
                    const int cx0 = min(max(ix, 0), 15), cx1 = min(max(ix + 1, 0), 15);
                    const int cy0 = min(max(iy, 0), 15), cy1 = min(max(iy + 1, 0), 15);
                    const h8 v00 = lds_nb[jj][cy0 * 16 + cx0];
                    const h8 v01 = lds_nb[jj][cy0 * 16 + cx1];
                    const h8 v10 = lds_nb[jj][cy1 * 16 + cx0];
                    const h8 v11 = lds_nb[jj][cy1 * 16 + cx1];
                    lds_rot[jj][p] =
                          v00 * splat8(mx0 * my0) + v01 * splat8(mx1 * my0)
                        + v10 * splat8(mx0 * my1) + v11 * splat8(mx1 * my1);
                }
            }
            __syncthreads();

            // ---- Phase B: pair-uniform 2x2 translation stencil ----
#pragma unroll
            for (int jj = 0; jj < 4; ++jj) {
                const int j = jj + (jj >= cur.i);
                if (j < cur.n) {
                    // all weights wave-uniform (SGPR) except the border masks
                    const float dx =  0.25f * cur.tr[jj][2];
                    const float dy = -0.25f * cur.tr[jj][5];
                    const float fdx = floorf(dx), fdy = floorf(dy);
                    const float tx1 = dx - fdx, tx0 = 1.0f - tx1;
                    const float ty1 = dy - fdy, ty0 = 1.0f - ty1;
                    const int ox = x + (int)fdx;
                    const int oy = y + (int)fdy;
                    const bool inx0 = (ox     >= 0) && (ox     < 16);
                    const bool inx1 = (ox + 1 >= 0) && (ox + 1 < 16);
                    const bool iny0 = (oy     >= 0) && (oy     < 16);
                    const bool iny1 = (oy + 1 >= 0) && (oy + 1 < 16);
                    const float w00 = (inx0 && iny0) ? tx0 * ty0 : 0.0f;
                    const float w10 = (inx1 && iny0) ? tx1 * ty0 : 0.0f;
                    const float w01 = (inx0 && iny1) ? tx0 * ty1 : 0.0f;
                    const float w11 = (inx1 && iny1) ? tx1 * ty1 : 0.0f;
                    const int cx0 = min(max(ox, 0), 15), cx1 = min(max(ox + 1, 0), 15);
                    const int cy0 = min(max(oy, 0), 15), cy1 = min(max(oy + 1, 0), 15);
                    const h8 t00 = lds_rot[jj][cy0 * 16 + cx0];
                    const h8 t01 = lds_rot[jj][cy0 * 16 + cx1];
                    const h8 t10 = lds_rot[jj][cy1 * 16 + cx0];
                    const h8 t11 = lds_rot[jj][cy1 * 16 + cx1];
                    const h8 s = t00 * splat8(w00) + t01 * splat8(w10)
                               + t10 * splat8(w01) + t11 * splat8(w11);
#pragma unroll
                    for (int k = 0; k < 8; ++k) psum[k] += (float)s[k];  // f32 accum
                }
            }
        }

        float* dst = out + ((cur.i * NB + cur.b) * NC + cur.c0) * HW + p;
#pragma unroll
        for (int k = 0; k < 8; ++k) dst[k * HW] = ownv[k] + psum[k];

        if (!more) break;
        cur = nxt;
        idx = nidx;
    }
}

extern "C" void kernel_launch(void* const* d_in, const int* in_sizes, int n_in,
                              void* d_out, int out_size, void* d_ws, size_t ws_size,
                              hipStream_t stream) {
    const float* feat  = (const float*)d_in[0];
    const float* trans = (const float*)d_in[1];
    const int*   numa  = (const int*)d_in[2];
    float* out = (float*)d_out;

    fafmimo_twophase2_kernel<<<dim3(NBLK), dim3(256), 0, stream>>>(
        feat, trans, numa, out);
}